// Round 22
// baseline (512.720 us; speedup 1.0000x reference)
//
#include <hip/hip_runtime.h>
#include <math.h>
#include <stdint.h>
#include <stddef.h>

// ---------------------------------------------------------------------------
// Attention layer for MI355X (gfx950). I/O fp32; internal bf16 MFMA pipeline.
//   cvt_all: x/wq/wk/wv -> bf16
//   qkv_proj8: 192 GEMM blocks (256x256, 8-phase cross-phase reg prefetch,
//       RoPE fused in epilogue) + 64 plain wo-cvt blocks.
//   oproj_tl: 128x128 dual-block TLP GEMM (r19-measured ~53us).
//   flash_attn: K LDS-staged (r4 swizzle), V read DIRECT from global
//       (r14 head clustering makes each XCD's KV 1MB = L2-resident; guide
//       m169: staging L2-fit data is pure overhead). V loads issued at
//       step top, covered by K-MFMAs + softmax. LDS 64->32KB.
// Only mfma_f32_16x16x32_bf16 is used (HW-verified layouts m89/m97).
// ---------------------------------------------------------------------------

typedef __attribute__((ext_vector_type(8))) short bf16x8;
typedef __attribute__((ext_vector_type(4))) short bf16x4;
typedef __attribute__((ext_vector_type(4))) float f32x4;
typedef unsigned short u16;
typedef unsigned int u32;

#define NEG_BIG (-1.0e9f)
#define MFMA32(a, b, c) __builtin_amdgcn_mfma_f32_16x16x32_bf16(a, b, c, 0, 0, 0)
#define SFENCE() __builtin_amdgcn_sched_barrier(0)
#define BAR() __builtin_amdgcn_s_barrier()
#define VMW(n_) asm volatile("s_waitcnt vmcnt(" #n_ ")" ::: "memory")

__device__ __forceinline__ float bf2f(u16 b) {
    return __uint_as_float(((unsigned int)b) << 16);
}
__device__ __forceinline__ u16 f2bf(float f) {
    unsigned int u = __float_as_uint(f);
    u += 0x7fff + ((u >> 16) & 1);   // RNE
    return (u16)(u >> 16);
}
__device__ __forceinline__ void gld_lds16(short* lds, const u16* g) {
    __builtin_amdgcn_global_load_lds(
        (const __attribute__((address_space(1))) void*)g,
        (__attribute__((address_space(3))) void*)lds, 16, 0, 0);
}
__device__ __forceinline__ void cvt8(const float* __restrict__ s,
                                     u16* __restrict__ d, int i) {
    float4 a, c;
    __builtin_memcpy(&a, s + i, 16);
    __builtin_memcpy(&c, s + i + 4, 16);
    bf16x8 o;
    o[0] = (short)f2bf(a.x); o[1] = (short)f2bf(a.y);
    o[2] = (short)f2bf(a.z); o[3] = (short)f2bf(a.w);
    o[4] = (short)f2bf(c.x); o[5] = (short)f2bf(c.y);
    o[6] = (short)f2bf(c.z); o[7] = (short)f2bf(c.w);
    __builtin_memcpy(d + i, &o, 16);
}

// ---------------------------------------------------------------------------
// fused fp32 -> bf16 convert: x | wq | wk | wv (wo moved into qkv_proj8)
// ---------------------------------------------------------------------------
__global__ __launch_bounds__(256) void cvt_all(
    const float* __restrict__ x, const float* __restrict__ wq,
    const float* __restrict__ wk, const float* __restrict__ wv,
    u16* __restrict__ xb, u16* __restrict__ wqb, u16* __restrict__ wkb,
    u16* __restrict__ wvb) {
    const int b = blockIdx.x;
    const float* s; u16* d; int off;
    if (b < 4096)       { s = x;  d = xb;  off = b; }
    else if (b < 12288) { s = wq; d = wqb; off = b - 4096; }
    else if (b < 14336) { s = wk; d = wkb; off = b - 12288; }
    else                { s = wv; d = wvb; off = b - 14336; }
    cvt8(s, d, off * 2048 + threadIdx.x * 8);
}

// ---------------------------------------------------------------------------
// qkv GEMM, BM=BN=256, BK=64, 512 threads (8 waves, 2M x 4N), MH=2.
// r7 structure + r12 in-epilogue RoPE. Cross-phase register prefetch;
// vmcnt(6) at even-phase ends; T2 swizzle (verified r4).
// ---------------------------------------------------------------------------

#define QSTGA(bf_, ks_, kt_)                                                 \
    { _Pragma("unroll") for (int r_ = 0; r_ < 2; ++r_)                       \
        gld_lds16(Ad + (bf_) * 16384 + (ks_) * 8192 + r_ * 4096,             \
                  Ag + gK * r_ + (size_t)(kt_) * 64 + (ks_) * 32); }
#define QSTGB(bf_, ks_, kt_)                                                 \
    { _Pragma("unroll") for (int r_ = 0; r_ < 2; ++r_)                       \
        gld_lds16(Bd + (bf_) * 16384 + (ks_) * 8192 + r_ * 4096,             \
                  Bg + gK * r_ + (size_t)(kt_) * 64 + (ks_) * 32); }
#define QRDA(bank_, bf_, ks_, mh_)                                           \
    { _Pragma("unroll") for (int i_ = 0; i_ < 4; ++i_)                       \
        __builtin_memcpy(&bank_[i_], S + (bf_) * 16384 + (ks_) * 8192 +      \
                         abase + ((mh_) * 64 + i_ * 16) * 32, 16); }
#define QRDB(bank_, bf_, ks_)                                                \
    { _Pragma("unroll") for (int n_ = 0; n_ < 4; ++n_)                       \
        __builtin_memcpy(&bank_[n_], Bs + (bf_) * 16384 + (ks_) * 8192 +     \
                         bbase + n_ * 512, 16); }
#define QMM(afb_, bfb_, mh_)                                                 \
    {                                                                        \
        __builtin_amdgcn_s_setprio(1);                                       \
        _Pragma("unroll") for (int i_ = 0; i_ < 4; ++i_)                     \
            _Pragma("unroll") for (int n_ = 0; n_ < 4; ++n_)                 \
                acc[(mh_) * 4 + i_][n_] =                                    \
                    MFMA32(afb_[i_], bfb_[n_], acc[(mh_) * 4 + i_][n_]);     \
        __builtin_amdgcn_s_setprio(0);                                       \
    }

template <int OUT, int ROPE>
__device__ __forceinline__ void gemm_q(const u16* __restrict__ A,
                                       const u16* __restrict__ B,
                                       void* __restrict__ C,
                                       const float* __restrict__ fc,
                                       const float* __restrict__ fs,
                                       int mb, int nb, int N, int K,
                                       short* __restrict__ S) {
    short* const Bs = S + 32768;
    const int t = threadIdx.x;
    const int lane = t & 63, l15 = lane & 15, quad = lane >> 4;
    const int wid = t >> 6, wr = wid >> 2, wc = wid & 3;

    const int srow = t >> 2;
    const int cs = (t & 3) ^ ((t >> 3) & 3);
    const u16* const Ag = A + (size_t)(mb * 256 + srow) * K + cs * 8;
    const u16* const Bg = B + (size_t)(nb * 256 + srow) * K + cs * 8;
    short* const Ad = S + t * 8;
    short* const Bd = Bs + t * 8;
    const size_t gK = (size_t)128 * K;

    const int swz = (quad ^ ((l15 >> 1) & 3)) * 8;
    const int abase = (wr * 128 + l15) * 32 + swz;
    const int bbase = (wc * 64 + l15) * 32 + swz;

    f32x4 acc[8][4] = {};
    bf16x8 af0[4], af1[4], bf0[4], bf1[4];

    QSTGA(0, 0, 0); QSTGB(0, 0, 0);
    QSTGA(0, 1, 0); QSTGB(0, 1, 0);
    QSTGA(1, 0, 1); QSTGB(1, 0, 1);
    VMW(8);
    BAR();
    QRDA(af0, 0, 0, 0); QRDB(bf0, 0, 0);
    SFENCE();

    const int nIt = K >> 7;
    for (int it = 0; it < nIt - 1; ++it) {
        const int k1 = 2 * it + 1, kn0 = 2 * it + 2, kn1 = 2 * it + 3;
        QSTGA(1, 1, k1);  QRDA(af1, 0, 0, 1);                    QMM(af0, bf0, 0); SFENCE(); VMW(6); BAR();
        QSTGB(1, 1, k1);  QRDA(af0, 0, 1, 0); QRDB(bf1, 0, 1);   QMM(af1, bf0, 1); SFENCE();         BAR();
        QSTGA(0, 0, kn0); QRDA(af1, 0, 1, 1);                    QMM(af0, bf1, 0); SFENCE(); VMW(6); BAR();
        QSTGB(0, 0, kn0); QRDA(af0, 1, 0, 0); QRDB(bf0, 1, 0);   QMM(af1, bf1, 1); SFENCE();         BAR();
        QSTGA(0, 1, kn0); QRDA(af1, 1, 0, 1);                    QMM(af0, bf0, 0); SFENCE(); VMW(6); BAR();
        QSTGB(0, 1, kn0); QRDA(af0, 1, 1, 0); QRDB(bf1, 1, 1);   QMM(af1, bf0, 1); SFENCE();         BAR();
        QSTGA(1, 0, kn1); QRDA(af1, 1, 1, 1);                    QMM(af0, bf1, 0); SFENCE(); VMW(6); BAR();
        QSTGB(1, 0, kn1); QRDA(af0, 0, 0, 0); QRDB(bf0, 0, 0);   QMM(af1, bf1, 1); SFENCE();         BAR();
    }
    {
        const int k1 = 2 * nIt - 1;
        QSTGA(1, 1, k1);  QRDA(af1, 0, 0, 1);                    QMM(af0, bf0, 0); SFENCE(); VMW(6); BAR();
        QSTGB(1, 1, k1);  QRDA(af0, 0, 1, 0); QRDB(bf1, 0, 1);   QMM(af1, bf0, 1); SFENCE();         BAR();
        QRDA(af1, 0, 1, 1);                                      QMM(af0, bf1, 0); SFENCE(); VMW(4); BAR();
        QRDA(af0, 1, 0, 0); QRDB(bf0, 1, 0);                     QMM(af1, bf1, 1); SFENCE();         BAR();
        QRDA(af1, 1, 0, 1);                                      QMM(af0, bf0, 0); SFENCE(); VMW(0); BAR();
        QRDA(af0, 1, 1, 0); QRDB(bf1, 1, 1);                     QMM(af1, bf0, 1); SFENCE();         BAR();
        QRDA(af1, 1, 1, 1);                                      QMM(af0, bf1, 0); SFENCE();         BAR();
        QMM(af1, bf1, 1);
    }

    // ---- epilogue. C/D layout: col = l15, row = quad*4 + r ----
#pragma unroll
    for (int i8 = 0; i8 < 8; ++i8) {
        const int rowb = mb * 256 + wr * 128 + (i8 >> 2) * 64 +
                         (i8 & 3) * 16 + quad * 4;
#pragma unroll
        for (int j = 0; j < 4; ++j) {
            const int col = nb * 256 + wc * 64 + j * 16 + l15;
            if (OUT == 2) {
                bf16x4 v;
#pragma unroll
                for (int r = 0; r < 4; ++r) v[r] = (short)f2bf(acc[i8][j][r]);
                __builtin_memcpy((u16*)C + (size_t)col * 2048 + rowb, &v, 8);
            } else if (ROPE) {
                // in-register RoPE: pair partner is the adjacent lane
                const int pi = (col & 127) >> 1;   // pair index 0..63
                const bool odd = (l15 & 1);
#pragma unroll
                for (int r = 0; r < 4; ++r) {
                    const int s = rowb + r;
                    const float c = fc[s * 64 + pi];
                    const float sn = fs[s * 64 + pi];
                    const float v = acc[i8][j][r];
                    const float vp = __shfl_xor(v, 1);
                    const float out = odd ? (vp * sn + v * c)
                                          : (v * c - vp * sn);
                    ((u16*)C)[(size_t)s * N + col] = f2bf(out);
                }
            } else {
#pragma unroll
                for (int r = 0; r < 4; ++r)
                    ((u16*)C)[(size_t)(rowb + r) * N + col] =
                        f2bf(acc[i8][j][r]);
            }
        }
    }
}

__global__ __launch_bounds__(512, 2) void qkv_proj8(
    const u16* __restrict__ x,
    const u16* __restrict__ wq, const u16* __restrict__ wk,
    const u16* __restrict__ wv,
    const float* __restrict__ wof, u16* __restrict__ wob,
    const float* __restrict__ fc, const float* __restrict__ fs,
    u16* __restrict__ Q, u16* __restrict__ Kc, u16* __restrict__ Vt) {
    __shared__ __align__(16) short S[65536];   // 128 KiB (GEMM blocks only)
    const int lid = blockIdx.x;
    if (lid >= 192) {
        // spare blocks (64): convert wo fp32->bf16 on idle CUs
        const int cb = lid - 192, t = threadIdx.x;
        for (int it = 0; it < 64; ++it)
            cvt8(wof, wob, ((cb * 64 + it) * 512 + t) * 8);
        return;
    }
    const int swzb = (lid & 7) * 24 + (lid >> 3);   // bijective XCD, 192=8x24
    const int mb = swzb & 7, y = swzb >> 3;
    if (y < 16)
        gemm_q<0, 1>(x, wq, Q, fc, fs, mb, y, 4096, 4096, S);
    else if (y < 20)
        gemm_q<0, 1>(x, wk, Kc, fc, fs, mb, y - 16, 1024, 4096, S);
    else
        gemm_q<2, 0>(x, wv, Vt, fc, fs, mb, y - 20, 1024, 4096, S);
}

// ---------------------------------------------------------------------------
// oproj_tl: r19-measured dual-block TLP GEMM (~53us). 128x128, BK=64,
// 256 threads (4 waves 2Mx2N), 64KB LDS -> 2 blocks/CU. 4-phase schedule,
// 4 gld/stage, vmcnt(8) ledger, peel 8/4/0. T2 swizzle (r4-verified).
// ---------------------------------------------------------------------------

#define OT_STG(bf_, ks_, kt_)                                                \
    {                                                                        \
        _Pragma("unroll") for (int r_ = 0; r_ < 2; ++r_)                     \
            gld_lds16(Ad + (bf_) * 8192 + (ks_) * 4096 + r_ * 2048,          \
                      Ag + g64 * r_ + (size_t)(kt_) * 64 + (ks_) * 32);      \
        _Pragma("unroll") for (int r_ = 0; r_ < 2; ++r_)                     \
            gld_lds16(Bd + (bf_) * 8192 + (ks_) * 4096 + r_ * 2048,          \
                      Bg + g64 * r_ + (size_t)(kt_) * 64 + (ks_) * 32);      \
    }
#define OT_PHASE(bf_, ks_, STAGE_, WAIT_)                                    \
    {                                                                        \
        _Pragma("unroll") for (int n_ = 0; n_ < 4; ++n_)                     \
            __builtin_memcpy(&bfr[n_], Bs + (bf_) * 8192 + (ks_) * 4096 +    \
                                           bbase + n_ * 512, 16);            \
        _Pragma("unroll") for (int i_ = 0; i_ < 4; ++i_)                     \
            __builtin_memcpy(&af[i_], S + (bf_) * 8192 + (ks_) * 4096 +      \
                                          abase + i_ * 512, 16);             \
        STAGE_;                                                              \
        SFENCE();                                                            \
        __builtin_amdgcn_s_barrier();                                        \
        asm volatile("s_waitcnt lgkmcnt(0)" ::: "memory");                   \
        SFENCE();                                                            \
        __builtin_amdgcn_s_setprio(1);                                       \
        _Pragma("unroll") for (int i_ = 0; i_ < 4; ++i_)                     \
            _Pragma("unroll") for (int n_ = 0; n_ < 4; ++n_)                 \
                acc[i_][n_] = MFMA32(af[i_], bfr[n_], acc[i_][n_]);          \
        __builtin_amdgcn_s_setprio(0);                                       \
        SFENCE();                                                            \
        WAIT_;                                                               \
        __builtin_amdgcn_s_barrier();                                        \
    }

__global__ __launch_bounds__(256, 2) void oproj_tl(
    const u16* __restrict__ A, const u16* __restrict__ wo,
    float* __restrict__ out) {
    __shared__ __align__(16) short S[32768];   // 64 KiB: A 2x8K, B 2x8K
    short* const Bs = S + 16384;
    const int lid = blockIdx.x;                // bijective XCD map, 512=8x64
    const int logical = (lid & 7) * 64 + (lid >> 3);
    const int mb = logical & 15, nb = logical >> 4;   // 16 x 32

    const int t = threadIdx.x;                 // 0..255
    const int lane = t & 63, l15 = lane & 15, quad = lane >> 4;
    const int wid = t >> 6, wr = wid >> 1, wc = wid & 1;

    const int srow = t >> 2;
    const int cs = (t & 3) ^ ((t >> 3) & 3);
    const u16* const Ag = A + (size_t)(mb * 128 + srow) * 4096 + cs * 8;
    const u16* const Bg = wo + (size_t)(nb * 128 + srow) * 4096 + cs * 8;
    short* const Ad = S + t * 8;
    short* const Bd = Bs + t * 8;
    const size_t g64 = (size_t)64 * 4096;

    const int swz = (quad ^ ((l15 >> 1) & 3)) * 8;
    const int abase = (wr * 64 + l15) * 32 + swz;
    const int bbase = (wc * 64 + l15) * 32 + swz;

    f32x4 acc[4][4] = {};
    bf16x8 af[4], bfr[4];

    OT_STG(0, 0, 0); OT_STG(0, 1, 0); OT_STG(1, 0, 1);
    VMW(8);   // b0.ks0 landed
    BAR();

    const int nIt = 32;
    for (int it = 0; it < nIt - 1; ++it) {
        const int k1 = 2 * it + 1, kn0 = 2 * it + 2, kn1 = 2 * it + 3;
        OT_PHASE(0, 0, OT_STG(1, 1, k1),  VMW(8));
        OT_PHASE(0, 1, OT_STG(0, 0, kn0), VMW(8));
        OT_PHASE(1, 0, OT_STG(0, 1, kn0), VMW(8));
        OT_PHASE(1, 1, OT_STG(1, 0, kn1), VMW(8));
    }
    {   // final iteration, peeled: drain
        const int k1 = 2 * nIt - 1;
        OT_PHASE(0, 0, OT_STG(1, 1, k1), VMW(8));
        OT_PHASE(0, 1, ,                 VMW(4));
        OT_PHASE(1, 0, ,                 VMW(0));
        OT_PHASE(1, 1, , );
    }

#pragma unroll
    for (int i = 0; i < 4; ++i) {
        const int rowb = mb * 128 + wr * 64 + i * 16 + quad * 4;
#pragma unroll
        for (int j = 0; j < 4; ++j) {
            const int col = nb * 128 + wc * 64 + j * 16 + l15;
#pragma unroll
            for (int r = 0; r < 4; ++r)
                out[(size_t)(rowb + r) * 4096 + col] = acc[i][j][r];
        }
    }
}

// ---------------------------------------------------------------------------
// Flash attention: K LDS-staged (r4 swizzle), V DIRECT from global.
// r14 head clustering -> each XCD's K+V = 1MB, L2-resident; V loads are
// L2 hits issued at step top (covered by K ds_reads + QK MFMAs + softmax).
// exp2-domain softmax; o9 ones-column row-sums; cvt_pk P-pack (r9).
// ---------------------------------------------------------------------------
__device__ __forceinline__ int kswz(int row, int cs) {
    int f = (row & 3) | ((row & 8) >> 1);
    return row * 128 + ((cs ^ f) << 3);
}

template <bool MASKED>
__device__ __forceinline__ void fa_step_lds(
    const short* __restrict__ Kl, const u16* __restrict__ vb,
    int kb, int kadd, int q0, int l15, int quad,
    const int (&koff)[8],
    const bf16x8 (&qf)[4], const bf16x8 vones,
    f32x4 (&o)[8], f32x4& o9, float& m) {
    const float c1 = 0.08838834764831845f * 1.4426950408889634f;

    // V frags: direct global reads (L2-hot), issued first for max cover
    bf16x8 vf[8];
#pragma unroll
    for (int n = 0; n < 8; ++n)
        __builtin_memcpy(&vf[n], vb + (size_t)n * 16 * 2048 + kb, 16);

    bf16x8 kf[8];
#pragma unroll
    for (int i = 0; i < 8; ++i)
        __builtin_memcpy(&kf[i], Kl + koff[i] + kadd, 16);
    f32x4 s0 = {0, 0, 0, 0}, s1 = {0, 0, 0, 0};
#pragma unroll
    for (int c = 0; c < 4; ++c) {
        s0 = MFMA32(kf[c], qf[c], s0);
        s1 = MFMA32(kf[4 + c], qf[c], s1);
    }

    float sv0[4], sv1[4];
    const int q = q0 + l15;
#pragma unroll
    for (int r = 0; r < 4; ++r) {
        sv0[r] = s0[r];
        sv1[r] = s1[r];
        if (MASKED) {
            if (kb + 8 * quad + r > q) sv0[r] = NEG_BIG;
            if (kb + 8 * quad + 4 + r > q) sv1[r] = NEG_BIG;
        }
    }

    float mx = fmaxf(fmaxf(fmaxf(sv0[0], sv0[1]), fmaxf(sv0[2], sv0[3])),
                     fmaxf(fmaxf(sv1[0], sv1[1]), fmaxf(sv1[2], sv1[3])));
    mx = fmaxf(mx, __shfl_xor(mx, 16));
    mx = fmaxf(mx, __shfl_xor(mx, 32));

    if (!__all(mx <= m + 90.0f)) {
        float mnew = fmaxf(m, mx);
        float alpha = exp2f((m - mnew) * c1);
        float aO[4];
#pragma unroll
        for (int r = 0; r < 4; ++r) aO[r] = __shfl(alpha, quad * 20 + r);
#pragma unroll
        for (int n = 0; n < 8; ++n)
#pragma unroll
            for (int r = 0; r < 4; ++r) o[n][r] *= aO[r];
#pragma unroll
        for (int r = 0; r < 4; ++r) o9[r] *= aO[r];
        m = mnew;
    }

    const float mc = m * c1;
    float p0[4], p1[4];
#pragma unroll
    for (int r = 0; r < 4; ++r) {
        p0[r] = exp2f(__builtin_fmaf(sv0[r], c1, -mc));
        p1[r] = exp2f(__builtin_fmaf(sv1[r], c1, -mc));
    }

    u32 w0, w1, w2, w3;
    asm("v_cvt_pk_bf16_f32 %0, %1, %2" : "=v"(w0) : "v"(p0[0]), "v"(p0[1]));
    asm("v_cvt_pk_bf16_f32 %0, %1, %2" : "=v"(w1) : "v"(p0[2]), "v"(p0[3]));
    asm("v_cvt_pk_bf16_f32 %0, %1, %2" : "=v"(w2) : "v"(p1[0]), "v"(p1[1]));
    asm("v_cvt_pk_bf16_f32 %0, %1, %2" : "=v"(w3) : "v"(p1[2]), "v"(p1[3]));
    u32 wa[4] = {w0, w1, w2, w3};
    bf16x8 pa;
    __builtin_memcpy(&pa, wa, 16);

#pragma unroll
    for (int n = 0; n < 8; ++n) o[n] = MFMA32(pa, vf[n], o[n]);
    o9 = MFMA32(pa, vones, o9);
}

__device__ __forceinline__ void fa_task(
    const u16* __restrict__ Q, const u16* __restrict__ Kc,
    const u16* __restrict__ Vt, u16* __restrict__ O,
    short* __restrict__ Kl0,
    int q0, int nbt64, int h, int kvh, int t) {
    const int lane = t & 63;
    const int l15 = lane & 15, quad = lane >> 4;

    bf16x8 qf[4];
    const u16* qp = Q + (size_t)(q0 + l15) * 4096 + h * 128 + quad * 8;
#pragma unroll
    for (int c = 0; c < 4; ++c) __builtin_memcpy(&qf[c], qp + c * 32, 16);

    bf16x8 vones;
#pragma unroll
    for (int i = 0; i < 8; ++i) vones[i] = (short)0x3F80;   // bf16 1.0

    // K staging (per-thread constants, 4 rounds)
    const u16* ksrc[4]; short* kdst[4];
#pragma unroll
    for (int r = 0; r < 4; ++r) {
        int row = (t >> 4) + 16 * r;            // K row 0..63
        int slot = t & 15;
        int f = (row & 3) | ((row & 8) >> 1);
        int cks = slot ^ f;
        ksrc[r] = Kc + (size_t)row * 1024 + kvh * 128 + cks * 8;
        kdst[r] = Kl0 + (t + 256 * r) * 8;
    }

    const int rk0 = 8 * (l15 >> 2) + (l15 & 3);   // key-permuted row (s0)
    int koff[8];
#pragma unroll
    for (int c = 0; c < 4; ++c) {
        koff[c] = kswz(rk0, quad + c * 4);
        koff[4 + c] = kswz(rk0 + 4, quad + c * 4);
    }
    // V per-lane base: row (kvh*128 + l15), key col quad*8 (kb added/step)
    const u16* const vb = Vt + (size_t)(kvh * 128 + l15) * 2048 + quad * 8;

    f32x4 o[8] = {};
    f32x4 o9 = {0, 0, 0, 0};
    float m = NEG_BIG;
    const int my_nb32 = (q0 + 47) / 32;   // causal 32-key sub-block count

#pragma unroll
    for (int r = 0; r < 4; ++r) gld_lds16(kdst[r], ksrc[r]);
    __syncthreads();

    for (int ib = 0; ib < nbt64; ++ib) {
        if (ib + 1 < nbt64) {
            const int kb = (ib + 1) * 64;
            const int bo = ((ib + 1) & 1) * 8192;
#pragma unroll
            for (int r = 0; r < 4; ++r)
                gld_lds16(kdst[r] + bo, ksrc[r] + (size_t)kb * 1024);
        }
        const short* Kl = Kl0 + (ib & 1) * 8192;
#pragma unroll
        for (int sub = 0; sub < 2; ++sub) {
            const int ib32 = 2 * ib + sub;
            if (ib32 < my_nb32) {   // wave-uniform predicate
                const int kb = ib * 64 + sub * 32;
                const int kadd = sub * 4096;
                if (ib32 == my_nb32 - 1)
                    fa_step_lds<true>(Kl, vb, kb, kadd, q0, l15, quad, koff,
                                      qf, vones, o, o9, m);
                else
                    fa_step_lds<false>(Kl, vb, kb, kadd, q0, l15, quad, koff,
                                       qf, vones, o, o9, m);
            }
        }
        __syncthreads();
    }

    float inv[4];
#pragma unroll
    for (int r = 0; r < 4; ++r) inv[r] = 1.f / o9[r];
#pragma unroll
    for (int n = 0; n < 8; ++n)
#pragma unroll
        for (int r = 0; r < 4; ++r) {
            int row = q0 + quad * 4 + r;
            O[(size_t)row * 4096 + h * 128 + n * 16 + l15] =
                f2bf(o[n][r] * inv[r]);
        }
}

__global__ __launch_bounds__(256, 2) void flash_attn(
    const u16* __restrict__ Q, const u16* __restrict__ Kc,
    const u16* __restrict__ Vt, u16* __restrict__ O) {
    __shared__ __align__(16) short Kl[2 * 64 * 128];   // 32 KiB (K only)
    // head-clustered 1-D map: presumed XCD c = id&7 serves kvh = c only.
    const int id = blockIdx.x;          // 0..511
    const int c = id & 7;
    const int j = id >> 3;              // 0..63
    const int h = 4 * c + (j & 3);      // heads 4c..4c+3
    const int pp = j >> 2;              // 0..15 (q-tile pair: pp and 31-pp)
    const int kvh = c;
    const int t = threadIdx.x, wave = t >> 6;
    fa_task(Q, Kc, Vt, O, Kl, pp * 64 + wave * 16, pp + 1, h, kvh, t);
    const int tb = 31 - pp;
    fa_task(Q, Kc, Vt, O, Kl, tb * 64 + (3 - wave) * 16, tb + 1, h, kvh, t);
}

// ---------------------------------------------------------------------------
extern "C" void kernel_launch(void* const* d_in, const int* in_sizes, int n_in,
                              void* d_out, int out_size, void* d_ws,
                              size_t ws_size, hipStream_t stream) {
    const float* x  = (const float*)d_in[0];
    const float* wq = (const float*)d_in[1];
    const float* wk = (const float*)d_in[2];
    const float* wv = (const float*)d_in[3];
    const float* wo = (const float*)d_in[4];
    const float* fc = (const float*)d_in[5];
    const float* fs = (const float*)d_in[6];
    float* out = (float*)d_out;

    const int NX = 2048 * 4096;
    const int NQW = 4096 * 4096;
    const int NKW = 1024 * 4096;
    const int NKV = 2048 * 1024;

    u16* Q   = (u16*)d_ws;
    u16* Kc  = Q   + NX;
    u16* Vt  = Kc  + NKV;   // [1024 features][2048 seq]
    u16* Ao  = Vt  + NKV;
    u16* xb  = Ao  + NX;
    u16* wqb = xb  + NX;
    u16* wkb = wqb + NQW;
    u16* wvb = wkb + NKW;
    u16* wob = wvb + NKW;

    cvt_all<<<16384, 256, 0, stream>>>(x, wq, wk, wv, xb, wqb, wkb, wvb);
    qkv_proj8<<<256, 512, 0, stream>>>(xb, wqb, wkb, wvb, wo, wob, fc, fs,
                                       Q, Kc, Vt);
    flash_attn<<<512, 256, 0, stream>>>(Q, Kc, Vt, Ao);
    oproj_tl<<<512, 256, 0, stream>>>(Ao, wob, out);
}

// Round 23
// 433.846 us; speedup vs baseline: 1.1818x; 1.1818x over previous
//
#include <hip/hip_runtime.h>
#include <math.h>
#include <stdint.h>
#include <stddef.h>

// ---------------------------------------------------------------------------
// Attention layer for MI355X (gfx950). I/O fp32; internal bf16 MFMA pipeline.
// FINAL SESSION CONFIGURATION (r19/r21-measured 442.4/436.5us):
//   cvt_all: x/wq/wk/wv -> bf16
//   qkv_proj8: 192 GEMM blocks (256x256, 8-phase cross-phase reg prefetch,
//       RoPE fused in epilogue) + 64 plain wo-cvt blocks.
//   oproj_tl: 128x128 dual-block TLP GEMM (2 blocks/CU barrier domains).
//   flash_attn: K+V LDS-staged paired KVBLK=64 (V-direct regressed r22:
//       global V reads uncoalesced at 4KB stride; gld_lds was coalescing
//       them into 1KB DMA bursts), head-clustered 1-D grid,
//       exp2-domain softmax + o9 ones-column row-sums + cvt_pk P-pack.
// Only mfma_f32_16x16x32_bf16 is used (HW-verified layouts m89/m97).
// ---------------------------------------------------------------------------

typedef __attribute__((ext_vector_type(8))) short bf16x8;
typedef __attribute__((ext_vector_type(4))) short bf16x4;
typedef __attribute__((ext_vector_type(4))) float f32x4;
typedef unsigned short u16;
typedef unsigned int u32;

#define NEG_BIG (-1.0e9f)
#define MFMA32(a, b, c) __builtin_amdgcn_mfma_f32_16x16x32_bf16(a, b, c, 0, 0, 0)
#define SFENCE() __builtin_amdgcn_sched_barrier(0)
#define BAR() __builtin_amdgcn_s_barrier()
#define VMW(n_) asm volatile("s_waitcnt vmcnt(" #n_ ")" ::: "memory")

__device__ __forceinline__ float bf2f(u16 b) {
    return __uint_as_float(((unsigned int)b) << 16);
}
__device__ __forceinline__ u16 f2bf(float f) {
    unsigned int u = __float_as_uint(f);
    u += 0x7fff + ((u >> 16) & 1);   // RNE
    return (u16)(u >> 16);
}
__device__ __forceinline__ void gld_lds16(short* lds, const u16* g) {
    __builtin_amdgcn_global_load_lds(
        (const __attribute__((address_space(1))) void*)g,
        (__attribute__((address_space(3))) void*)lds, 16, 0, 0);
}
__device__ __forceinline__ void cvt8(const float* __restrict__ s,
                                     u16* __restrict__ d, int i) {
    float4 a, c;
    __builtin_memcpy(&a, s + i, 16);
    __builtin_memcpy(&c, s + i + 4, 16);
    bf16x8 o;
    o[0] = (short)f2bf(a.x); o[1] = (short)f2bf(a.y);
    o[2] = (short)f2bf(a.z); o[3] = (short)f2bf(a.w);
    o[4] = (short)f2bf(c.x); o[5] = (short)f2bf(c.y);
    o[6] = (short)f2bf(c.z); o[7] = (short)f2bf(c.w);
    __builtin_memcpy(d + i, &o, 16);
}

// ---------------------------------------------------------------------------
// fused fp32 -> bf16 convert: x | wq | wk | wv (wo moved into qkv_proj8)
// ---------------------------------------------------------------------------
__global__ __launch_bounds__(256) void cvt_all(
    const float* __restrict__ x, const float* __restrict__ wq,
    const float* __restrict__ wk, const float* __restrict__ wv,
    u16* __restrict__ xb, u16* __restrict__ wqb, u16* __restrict__ wkb,
    u16* __restrict__ wvb) {
    const int b = blockIdx.x;
    const float* s; u16* d; int off;
    if (b < 4096)       { s = x;  d = xb;  off = b; }
    else if (b < 12288) { s = wq; d = wqb; off = b - 4096; }
    else if (b < 14336) { s = wk; d = wkb; off = b - 12288; }
    else                { s = wv; d = wvb; off = b - 14336; }
    cvt8(s, d, off * 2048 + threadIdx.x * 8);
}

// ---------------------------------------------------------------------------
// qkv GEMM, BM=BN=256, BK=64, 512 threads (8 waves, 2M x 4N), MH=2.
// r7 structure + r12 in-epilogue RoPE. Cross-phase register prefetch;
// vmcnt(6) at even-phase ends; T2 swizzle (verified r4).
// ---------------------------------------------------------------------------

#define QSTGA(bf_, ks_, kt_)                                                 \
    { _Pragma("unroll") for (int r_ = 0; r_ < 2; ++r_)                       \
        gld_lds16(Ad + (bf_) * 16384 + (ks_) * 8192 + r_ * 4096,             \
                  Ag + gK * r_ + (size_t)(kt_) * 64 + (ks_) * 32); }
#define QSTGB(bf_, ks_, kt_)                                                 \
    { _Pragma("unroll") for (int r_ = 0; r_ < 2; ++r_)                       \
        gld_lds16(Bd + (bf_) * 16384 + (ks_) * 8192 + r_ * 4096,             \
                  Bg + gK * r_ + (size_t)(kt_) * 64 + (ks_) * 32); }
#define QRDA(bank_, bf_, ks_, mh_)                                           \
    { _Pragma("unroll") for (int i_ = 0; i_ < 4; ++i_)                       \
        __builtin_memcpy(&bank_[i_], S + (bf_) * 16384 + (ks_) * 8192 +      \
                         abase + ((mh_) * 64 + i_ * 16) * 32, 16); }
#define QRDB(bank_, bf_, ks_)                                                \
    { _Pragma("unroll") for (int n_ = 0; n_ < 4; ++n_)                       \
        __builtin_memcpy(&bank_[n_], Bs + (bf_) * 16384 + (ks_) * 8192 +     \
                         bbase + n_ * 512, 16); }
#define QMM(afb_, bfb_, mh_)                                                 \
    {                                                                        \
        __builtin_amdgcn_s_setprio(1);                                       \
        _Pragma("unroll") for (int i_ = 0; i_ < 4; ++i_)                     \
            _Pragma("unroll") for (int n_ = 0; n_ < 4; ++n_)                 \
                acc[(mh_) * 4 + i_][n_] =                                    \
                    MFMA32(afb_[i_], bfb_[n_], acc[(mh_) * 4 + i_][n_]);     \
        __builtin_amdgcn_s_setprio(0);                                       \
    }

template <int OUT, int ROPE>
__device__ __forceinline__ void gemm_q(const u16* __restrict__ A,
                                       const u16* __restrict__ B,
                                       void* __restrict__ C,
                                       const float* __restrict__ fc,
                                       const float* __restrict__ fs,
                                       int mb, int nb, int N, int K,
                                       short* __restrict__ S) {
    short* const Bs = S + 32768;
    const int t = threadIdx.x;
    const int lane = t & 63, l15 = lane & 15, quad = lane >> 4;
    const int wid = t >> 6, wr = wid >> 2, wc = wid & 3;

    const int srow = t >> 2;
    const int cs = (t & 3) ^ ((t >> 3) & 3);
    const u16* const Ag = A + (size_t)(mb * 256 + srow) * K + cs * 8;
    const u16* const Bg = B + (size_t)(nb * 256 + srow) * K + cs * 8;
    short* const Ad = S + t * 8;
    short* const Bd = Bs + t * 8;
    const size_t gK = (size_t)128 * K;

    const int swz = (quad ^ ((l15 >> 1) & 3)) * 8;
    const int abase = (wr * 128 + l15) * 32 + swz;
    const int bbase = (wc * 64 + l15) * 32 + swz;

    f32x4 acc[8][4] = {};
    bf16x8 af0[4], af1[4], bf0[4], bf1[4];

    QSTGA(0, 0, 0); QSTGB(0, 0, 0);
    QSTGA(0, 1, 0); QSTGB(0, 1, 0);
    QSTGA(1, 0, 1); QSTGB(1, 0, 1);
    VMW(8);
    BAR();
    QRDA(af0, 0, 0, 0); QRDB(bf0, 0, 0);
    SFENCE();

    const int nIt = K >> 7;
    for (int it = 0; it < nIt - 1; ++it) {
        const int k1 = 2 * it + 1, kn0 = 2 * it + 2, kn1 = 2 * it + 3;
        QSTGA(1, 1, k1);  QRDA(af1, 0, 0, 1);                    QMM(af0, bf0, 0); SFENCE(); VMW(6); BAR();
        QSTGB(1, 1, k1);  QRDA(af0, 0, 1, 0); QRDB(bf1, 0, 1);   QMM(af1, bf0, 1); SFENCE();         BAR();
        QSTGA(0, 0, kn0); QRDA(af1, 0, 1, 1);                    QMM(af0, bf1, 0); SFENCE(); VMW(6); BAR();
        QSTGB(0, 0, kn0); QRDA(af0, 1, 0, 0); QRDB(bf0, 1, 0);   QMM(af1, bf1, 1); SFENCE();         BAR();
        QSTGA(0, 1, kn0); QRDA(af1, 1, 0, 1);                    QMM(af0, bf0, 0); SFENCE(); VMW(6); BAR();
        QSTGB(0, 1, kn0); QRDA(af0, 1, 1, 0); QRDB(bf1, 1, 1);   QMM(af1, bf0, 1); SFENCE();         BAR();
        QSTGA(1, 0, kn1); QRDA(af1, 1, 1, 1);                    QMM(af0, bf1, 0); SFENCE(); VMW(6); BAR();
        QSTGB(1, 0, kn1); QRDA(af0, 0, 0, 0); QRDB(bf0, 0, 0);   QMM(af1, bf1, 1); SFENCE();         BAR();
    }
    {
        const int k1 = 2 * nIt - 1;
        QSTGA(1, 1, k1);  QRDA(af1, 0, 0, 1);                    QMM(af0, bf0, 0); SFENCE(); VMW(6); BAR();
        QSTGB(1, 1, k1);  QRDA(af0, 0, 1, 0); QRDB(bf1, 0, 1);   QMM(af1, bf0, 1); SFENCE();         BAR();
        QRDA(af1, 0, 1, 1);                                      QMM(af0, bf1, 0); SFENCE(); VMW(4); BAR();
        QRDA(af0, 1, 0, 0); QRDB(bf0, 1, 0);                     QMM(af1, bf1, 1); SFENCE();         BAR();
        QRDA(af1, 1, 0, 1);                                      QMM(af0, bf0, 0); SFENCE(); VMW(0); BAR();
        QRDA(af0, 1, 1, 0); QRDB(bf1, 1, 1);                     QMM(af1, bf0, 1); SFENCE();         BAR();
        QRDA(af1, 1, 1, 1);                                      QMM(af0, bf1, 0); SFENCE();         BAR();
        QMM(af1, bf1, 1);
    }

    // ---- epilogue. C/D layout: col = l15, row = quad*4 + r ----
#pragma unroll
    for (int i8 = 0; i8 < 8; ++i8) {
        const int rowb = mb * 256 + wr * 128 + (i8 >> 2) * 64 +
                         (i8 & 3) * 16 + quad * 4;
#pragma unroll
        for (int j = 0; j < 4; ++j) {
            const int col = nb * 256 + wc * 64 + j * 16 + l15;
            if (OUT == 2) {
                bf16x4 v;
#pragma unroll
                for (int r = 0; r < 4; ++r) v[r] = (short)f2bf(acc[i8][j][r]);
                __builtin_memcpy((u16*)C + (size_t)col * 2048 + rowb, &v, 8);
            } else if (ROPE) {
                // in-register RoPE: pair partner is the adjacent lane
                const int pi = (col & 127) >> 1;   // pair index 0..63
                const bool odd = (l15 & 1);
#pragma unroll
                for (int r = 0; r < 4; ++r) {
                    const int s = rowb + r;
                    const float c = fc[s * 64 + pi];
                    const float sn = fs[s * 64 + pi];
                    const float v = acc[i8][j][r];
                    const float vp = __shfl_xor(v, 1);
                    const float out = odd ? (vp * sn + v * c)
                                          : (v * c - vp * sn);
                    ((u16*)C)[(size_t)s * N + col] = f2bf(out);
                }
            } else {
#pragma unroll
                for (int r = 0; r < 4; ++r)
                    ((u16*)C)[(size_t)(rowb + r) * N + col] =
                        f2bf(acc[i8][j][r]);
            }
        }
    }
}

__global__ __launch_bounds__(512, 2) void qkv_proj8(
    const u16* __restrict__ x,
    const u16* __restrict__ wq, const u16* __restrict__ wk,
    const u16* __restrict__ wv,
    const float* __restrict__ wof, u16* __restrict__ wob,
    const float* __restrict__ fc, const float* __restrict__ fs,
    u16* __restrict__ Q, u16* __restrict__ Kc, u16* __restrict__ Vt) {
    __shared__ __align__(16) short S[65536];   // 128 KiB (GEMM blocks only)
    const int lid = blockIdx.x;
    if (lid >= 192) {
        // spare blocks (64): convert wo fp32->bf16 on idle CUs
        const int cb = lid - 192, t = threadIdx.x;
        for (int it = 0; it < 64; ++it)
            cvt8(wof, wob, ((cb * 64 + it) * 512 + t) * 8);
        return;
    }
    const int swzb = (lid & 7) * 24 + (lid >> 3);   // bijective XCD, 192=8x24
    const int mb = swzb & 7, y = swzb >> 3;
    if (y < 16)
        gemm_q<0, 1>(x, wq, Q, fc, fs, mb, y, 4096, 4096, S);
    else if (y < 20)
        gemm_q<0, 1>(x, wk, Kc, fc, fs, mb, y - 16, 1024, 4096, S);
    else
        gemm_q<2, 0>(x, wv, Vt, fc, fs, mb, y - 20, 1024, 4096, S);
}

// ---------------------------------------------------------------------------
// oproj_tl: r19-measured dual-block TLP GEMM (~53us). 128x128, BK=64,
// 256 threads (4 waves 2Mx2N), 64KB LDS -> 2 blocks/CU. 4-phase schedule,
// 4 gld/stage, vmcnt(8) ledger, peel 8/4/0. T2 swizzle (r4-verified).
// ---------------------------------------------------------------------------

#define OT_STG(bf_, ks_, kt_)                                                \
    {                                                                        \
        _Pragma("unroll") for (int r_ = 0; r_ < 2; ++r_)                     \
            gld_lds16(Ad + (bf_) * 8192 + (ks_) * 4096 + r_ * 2048,          \
                      Ag + g64 * r_ + (size_t)(kt_) * 64 + (ks_) * 32);      \
        _Pragma("unroll") for (int r_ = 0; r_ < 2; ++r_)                     \
            gld_lds16(Bd + (bf_) * 8192 + (ks_) * 4096 + r_ * 2048,          \
                      Bg + g64 * r_ + (size_t)(kt_) * 64 + (ks_) * 32);      \
    }
#define OT_PHASE(bf_, ks_, STAGE_, WAIT_)                                    \
    {                                                                        \
        _Pragma("unroll") for (int n_ = 0; n_ < 4; ++n_)                     \
            __builtin_memcpy(&bfr[n_], Bs + (bf_) * 8192 + (ks_) * 4096 +    \
                                           bbase + n_ * 512, 16);            \
        _Pragma("unroll") for (int i_ = 0; i_ < 4; ++i_)                     \
            __builtin_memcpy(&af[i_], S + (bf_) * 8192 + (ks_) * 4096 +      \
                                          abase + i_ * 512, 16);             \
        STAGE_;                                                              \
        SFENCE();                                                            \
        __builtin_amdgcn_s_barrier();                                        \
        asm volatile("s_waitcnt lgkmcnt(0)" ::: "memory");                   \
        SFENCE();                                                            \
        __builtin_amdgcn_s_setprio(1);                                       \
        _Pragma("unroll") for (int i_ = 0; i_ < 4; ++i_)                     \
            _Pragma("unroll") for (int n_ = 0; n_ < 4; ++n_)                 \
                acc[i_][n_] = MFMA32(af[i_], bfr[n_], acc[i_][n_]);          \
        __builtin_amdgcn_s_setprio(0);                                       \
        SFENCE();                                                            \
        WAIT_;                                                               \
        __builtin_amdgcn_s_barrier();                                        \
    }

__global__ __launch_bounds__(256, 2) void oproj_tl(
    const u16* __restrict__ A, const u16* __restrict__ wo,
    float* __restrict__ out) {
    __shared__ __align__(16) short S[32768];   // 64 KiB: A 2x8K, B 2x8K
    short* const Bs = S + 16384;
    const int lid = blockIdx.x;                // bijective XCD map, 512=8x64
    const int logical = (lid & 7) * 64 + (lid >> 3);
    const int mb = logical & 15, nb = logical >> 4;   // 16 x 32

    const int t = threadIdx.x;                 // 0..255
    const int lane = t & 63, l15 = lane & 15, quad = lane >> 4;
    const int wid = t >> 6, wr = wid >> 1, wc = wid & 1;

    const int srow = t >> 2;
    const int cs = (t & 3) ^ ((t >> 3) & 3);
    const u16* const Ag = A + (size_t)(mb * 128 + srow) * 4096 + cs * 8;
    const u16* const Bg = wo + (size_t)(nb * 128 + srow) * 4096 + cs * 8;
    short* const Ad = S + t * 8;
    short* const Bd = Bs + t * 8;
    const size_t g64 = (size_t)64 * 4096;

    const int swz = (quad ^ ((l15 >> 1) & 3)) * 8;
    const int abase = (wr * 64 + l15) * 32 + swz;
    const int bbase = (wc * 64 + l15) * 32 + swz;

    f32x4 acc[4][4] = {};
    bf16x8 af[4], bfr[4];

    OT_STG(0, 0, 0); OT_STG(0, 1, 0); OT_STG(1, 0, 1);
    VMW(8);   // b0.ks0 landed
    BAR();

    const int nIt = 32;
    for (int it = 0; it < nIt - 1; ++it) {
        const int k1 = 2 * it + 1, kn0 = 2 * it + 2, kn1 = 2 * it + 3;
        OT_PHASE(0, 0, OT_STG(1, 1, k1),  VMW(8));
        OT_PHASE(0, 1, OT_STG(0, 0, kn0), VMW(8));
        OT_PHASE(1, 0, OT_STG(0, 1, kn0), VMW(8));
        OT_PHASE(1, 1, OT_STG(1, 0, kn1), VMW(8));
    }
    {   // final iteration, peeled: drain
        const int k1 = 2 * nIt - 1;
        OT_PHASE(0, 0, OT_STG(1, 1, k1), VMW(8));
        OT_PHASE(0, 1, ,                 VMW(4));
        OT_PHASE(1, 0, ,                 VMW(0));
        OT_PHASE(1, 1, , );
    }

#pragma unroll
    for (int i = 0; i < 4; ++i) {
        const int rowb = mb * 128 + wr * 64 + i * 16 + quad * 4;
#pragma unroll
        for (int j = 0; j < 4; ++j) {
            const int col = nb * 128 + wc * 64 + j * 16 + l15;
#pragma unroll
            for (int r = 0; r < 4; ++r)
                out[(size_t)(rowb + r) * 4096 + col] = acc[i][j][r];
        }
    }
}

// ---------------------------------------------------------------------------
// Flash attention (r12 paired KVBLK=64 form) + r14 head-clustered 1-D grid.
// exp2-domain softmax; o9 ones-column row-sums; cvt_pk P-pack (r9).
// K swizzle as r4 (2-way, free); V [128][64] slot^(row&7) swizzle (r8).
// ---------------------------------------------------------------------------
__device__ __forceinline__ int kswz(int row, int cs) {
    int f = (row & 3) | ((row & 8) >> 1);
    return row * 128 + ((cs ^ f) << 3);
}

template <bool MASKED>
__device__ __forceinline__ void fa_step_lds(
    const short* __restrict__ Kl, const short* __restrict__ Vl,
    int kb, int kadd, int q0, int l15, int quad,
    const int (&koff)[8], const int (&voff)[8],
    const bf16x8 (&qf)[4], const bf16x8 vones,
    f32x4 (&o)[8], f32x4& o9, float& m) {
    const float c1 = 0.08838834764831845f * 1.4426950408889634f;

    bf16x8 kf[8];
#pragma unroll
    for (int i = 0; i < 8; ++i)
        __builtin_memcpy(&kf[i], Kl + koff[i] + kadd, 16);
    f32x4 s0 = {0, 0, 0, 0}, s1 = {0, 0, 0, 0};
#pragma unroll
    for (int c = 0; c < 4; ++c) {
        s0 = MFMA32(kf[c], qf[c], s0);
        s1 = MFMA32(kf[4 + c], qf[c], s1);
    }

    bf16x8 vf[8];
#pragma unroll
    for (int n = 0; n < 8; ++n) __builtin_memcpy(&vf[n], Vl + voff[n], 16);

    float sv0[4], sv1[4];
    const int q = q0 + l15;
#pragma unroll
    for (int r = 0; r < 4; ++r) {
        sv0[r] = s0[r];
        sv1[r] = s1[r];
        if (MASKED) {
            if (kb + 8 * quad + r > q) sv0[r] = NEG_BIG;
            if (kb + 8 * quad + 4 + r > q) sv1[r] = NEG_BIG;
        }
    }

    float mx = fmaxf(fmaxf(fmaxf(sv0[0], sv0[1]), fmaxf(sv0[2], sv0[3])),
                     fmaxf(fmaxf(sv1[0], sv1[1]), fmaxf(sv1[2], sv1[3])));
    mx = fmaxf(mx, __shfl_xor(mx, 16));
    mx = fmaxf(mx, __shfl_xor(mx, 32));

    if (!__all(mx <= m + 90.0f)) {
        float mnew = fmaxf(m, mx);
        float alpha = exp2f((m - mnew) * c1);
        float aO[4];
#pragma unroll
        for (int r = 0; r < 4; ++r) aO[r] = __shfl(alpha, quad * 20 + r);
#pragma unroll
        for (int n = 0; n < 8; ++n)
#pragma unroll
            for (int r = 0; r < 4; ++r) o[n][r] *= aO[r];
#pragma unroll
        for (int r = 0; r < 4; ++r) o9[r] *= aO[r];
        m = mnew;
    }

    const float mc = m * c1;
    float p0[4], p1[4];
#pragma unroll
    for (int r = 0; r < 4; ++r) {
        p0[r] = exp2f(__builtin_fmaf(sv0[r], c1, -mc));
        p1[r] = exp2f(__builtin_fmaf(sv1[r], c1, -mc));
    }

    u32 w0, w1, w2, w3;
    asm("v_cvt_pk_bf16_f32 %0, %1, %2" : "=v"(w0) : "v"(p0[0]), "v"(p0[1]));
    asm("v_cvt_pk_bf16_f32 %0, %1, %2" : "=v"(w1) : "v"(p0[2]), "v"(p0[3]));
    asm("v_cvt_pk_bf16_f32 %0, %1, %2" : "=v"(w2) : "v"(p1[0]), "v"(p1[1]));
    asm("v_cvt_pk_bf16_f32 %0, %1, %2" : "=v"(w3) : "v"(p1[2]), "v"(p1[3]));
    u32 wa[4] = {w0, w1, w2, w3};
    bf16x8 pa;
    __builtin_memcpy(&pa, wa, 16);

#pragma unroll
    for (int n = 0; n < 8; ++n) o[n] = MFMA32(pa, vf[n], o[n]);
    o9 = MFMA32(pa, vones, o9);
}

__device__ __forceinline__ void fa_task(
    const u16* __restrict__ Q, const u16* __restrict__ Kc,
    const u16* __restrict__ Vt, u16* __restrict__ O,
    short* __restrict__ Kl0, short* __restrict__ Vl0,
    int q0, int nbt64, int h, int kvh, int t) {
    const int lane = t & 63;
    const int l15 = lane & 15, quad = lane >> 4;

    bf16x8 qf[4];
    const u16* qp = Q + (size_t)(q0 + l15) * 4096 + h * 128 + quad * 8;
#pragma unroll
    for (int c = 0; c < 4; ++c) __builtin_memcpy(&qf[c], qp + c * 32, 16);

    bf16x8 vones;
#pragma unroll
    for (int i = 0; i < 8; ++i) vones[i] = (short)0x3F80;   // bf16 1.0

    const u16* ksrc[4]; short* kdst[4];
    const u16* vsrc[4]; short* vdst[4];
#pragma unroll
    for (int r = 0; r < 4; ++r) {
        int row = (t >> 4) + 16 * r;            // K row 0..63
        int slot = t & 15;
        int f = (row & 3) | ((row & 8) >> 1);
        int cks = slot ^ f;
        ksrc[r] = Kc + (size_t)row * 1024 + kvh * 128 + cks * 8;
        kdst[r] = Kl0 + (t + 256 * r) * 8;
        int rowv = (t >> 3) + 32 * r;           // V row 0..127
        int csv = (t & 7) ^ ((t >> 3) & 7);     // inverse of V read swizzle
        vsrc[r] = Vt + (size_t)(kvh * 128 + rowv) * 2048 + csv * 8;
        vdst[r] = Vl0 + (t + 256 * r) * 8;
    }

    const int rk0 = 8 * (l15 >> 2) + (l15 & 3);   // key-permuted row (s0)
    int koff[8], voff0[8], voff1[8];
#pragma unroll
    for (int c = 0; c < 4; ++c) {
        koff[c] = kswz(rk0, quad + c * 4);
        koff[4 + c] = kswz(rk0 + 4, quad + c * 4);
    }
#pragma unroll
    for (int n = 0; n < 8; ++n) {
        const int row = n * 16 + l15;
        voff0[n] = row * 64 + ((quad ^ (l15 & 7)) << 3);
        voff1[n] = row * 64 + (((quad + 4) ^ (l15 & 7)) << 3);
    }

    f32x4 o[8] = {};
    f32x4 o9 = {0, 0, 0, 0};
    float m = NEG_BIG;
    const int my_nb32 = (q0 + 47) / 32;   // causal 32-key sub-block count

#pragma unroll
    for (int r = 0; r < 4; ++r) {
        gld_lds16(kdst[r], ksrc[r]);
        gld_lds16(vdst[r], vsrc[r]);
    }
    __syncthreads();

    for (int ib = 0; ib < nbt64; ++ib) {
        if (ib + 1 < nbt64) {
            const int kb = (ib + 1) * 64;
            const int bo = ((ib + 1) & 1) * 8192;
#pragma unroll
            for (int r = 0; r < 4; ++r) {
                gld_lds16(kdst[r] + bo, ksrc[r] + (size_t)kb * 1024);
                gld_lds16(vdst[r] + bo, vsrc[r] + kb);
            }
        }
        const short* Kl = Kl0 + (ib & 1) * 8192;
        const short* Vl = Vl0 + (ib & 1) * 8192;
#pragma unroll
        for (int sub = 0; sub < 2; ++sub) {
            const int ib32 = 2 * ib + sub;
            if (ib32 < my_nb32) {   // wave-uniform predicate
                const int kb = ib * 64 + sub * 32;
                const int kadd = sub * 4096;
                if (ib32 == my_nb32 - 1)
                    fa_step_lds<true>(Kl, Vl, kb, kadd, q0, l15, quad, koff,
                                      sub ? voff1 : voff0, qf, vones, o, o9,
                                      m);
                else
                    fa_step_lds<false>(Kl, Vl, kb, kadd, q0, l15, quad, koff,
                                       sub ? voff1 : voff0, qf, vones, o, o9,
                                       m);
            }
        }
        __syncthreads();
    }

    float inv[4];
#pragma unroll
    for (int r = 0; r < 4; ++r) inv[r] = 1.f / o9[r];
#pragma unroll
    for (int n = 0; n < 8; ++n)
#pragma unroll
        for (int r = 0; r < 4; ++r) {
            int row = q0 + quad * 4 + r;
            O[(size_t)row * 4096 + h * 128 + n * 16 + l15] =
                f2bf(o[n][r] * inv[r]);
        }
}

__global__ __launch_bounds__(256, 2) void flash_attn(
    const u16* __restrict__ Q, const u16* __restrict__ Kc,
    const u16* __restrict__ Vt, u16* __restrict__ O) {
    __shared__ __align__(16) short Kl[2 * 64 * 128];   // 32 KiB
    __shared__ __align__(16) short Vl[2 * 128 * 64];   // 32 KiB
    // head-clustered 1-D map: presumed XCD c = id&7 serves kvh = c only.
    const int id = blockIdx.x;          // 0..511
    const int c = id & 7;
    const int j = id >> 3;              // 0..63
    const int h = 4 * c + (j & 3);      // heads 4c..4c+3
    const int pp = j >> 2;              // 0..15 (q-tile pair: pp and 31-pp)
    const int kvh = c;
    const int t = threadIdx.x, wave = t >> 6;
    fa_task(Q, Kc, Vt, O, Kl, Vl, pp * 64 + wave * 16, pp + 1, h, kvh, t);
    const int tb = 31 - pp;
    fa_task(Q, Kc, Vt, O, Kl, Vl, tb * 64 + (3 - wave) * 16, tb + 1, h,
            kvh, t);
}

// ---------------------------------------------------------------------------
extern "C" void kernel_launch(void* const* d_in, const int* in_sizes, int n_in,
                              void* d_out, int out_size, void* d_ws,
                              size_t ws_size, hipStream_t stream) {
    const float* x  = (const float*)d_in[0];
    const float* wq = (const float*)d_in[1];
    const float* wk = (const float*)d_in[2];
    const float* wv = (const float*)d_in[3];
    const float* wo = (const float*)d_in[4];
    const float* fc = (const float*)d_in[5];
    const float* fs = (const float*)d_in[6];
    float* out = (float*)d_out;

    const int NX = 2048 * 4096;
    const int NQW = 4096 * 4096;
    const int NKW = 1024 * 4096;
    const int NKV = 2048 * 1024;

    u16* Q   = (u16*)d_ws;
    u16* Kc  = Q   + NX;
    u16* Vt  = Kc  + NKV;   // [1024 features][2048 seq]
    u16* Ao  = Vt  + NKV;
    u16* xb  = Ao  + NX;
    u16* wqb = xb  + NX;
    u16* wkb = wqb + NQW;
    u16* wvb = wkb + NKW;
    u16* wob = wvb + NKW;

    cvt_all<<<16384, 256, 0, stream>>>(x, wq, wk, wv, xb, wqb, wkb, wvb);
    qkv_proj8<<<256, 512, 0, stream>>>(xb, wqb, wkb, wvb, wo, wob, fc, fs,
                                       Q, Kc, Vt);
    flash_attn<<<512, 256, 0, stream>>>(Q, Kc, Vt, Ao);
    oproj_tl<<<512, 256, 0, stream>>>(Ao, wob, out);
}